// Round 5
// baseline (595.840 us; speedup 1.0000x reference)
//
#include <hip/hip_runtime.h>
#include <stdint.h>

typedef unsigned long long u64;

#define N 8192
#define NW 128            // 64-bit words per mask row
#define MAX_OUT 256
#define GRID 512
#define MASK_BYTES ((size_t)N * NW * 8)   // 8 MiB

// ws layout:
//   [0, 8MB)    mask u64[N][NW]
//     overlap (dead before mask phase writes):
//       ws+0    rank_part int[16][N] (512 KB)
//   +8MB        order  int[N]     32 KB
//   +32KB       s_s    float[N]   32 KB
//   +64KB       bbox   float4[N] 128 KB
//   +192KB      area   float[N]   32 KB
//   +224KB      barrier counters: 3 barriers x 8 counters (zeroed via memsetAsync)

__device__ __forceinline__ u64 score_key(float s, int idx) {
    // non-negative floats: uint bit pattern order-preserving.
    // ~bits<<32 | idx → ascending == score desc, idx asc (stable argsort).
    uint32_t b = __float_as_uint(s);
    return ((u64)(~b) << 32) | (uint32_t)idx;
}

// Exact ref-op-order IoU decision (bit-exact vs numpy, proven R1-R4).
__device__ __forceinline__ bool iou_gt(float4 a, float aa, float4 b, float ja) {
    float lx = fmaxf(a.x, b.x), ly = fmaxf(a.y, b.y);
    float rx = fminf(a.z, b.z), ry = fminf(a.w, b.w);
    float ww = fmaxf(rx - lx, 0.0f), hh = fmaxf(ry - ly, 0.0f);
    float inter = ww * hh;
    float denom = ((aa + ja) - inter) + 1e-9f;  // exact ref op order
    float iou = inter / denom;                   // IEEE div, matches np
    return iou > 0.3f;
}

__device__ __forceinline__ u64 shfl_u64(u64 v, int src) {
    unsigned lo = __shfl((unsigned)v, src);
    unsigned hi = __shfl((unsigned)(v >> 32), src);
    return ((u64)hi << 32) | lo;
}

// Device-scope grid barrier; 8-way-split counters to cut atomic contention.
__device__ __forceinline__ void gbar(unsigned* c8, bool spin) {
    __threadfence();
    __syncthreads();
    if (threadIdx.x == 0) {
        __hip_atomic_fetch_add(&c8[blockIdx.x & 7], 1u, __ATOMIC_RELEASE,
                               __HIP_MEMORY_SCOPE_AGENT);
        if (spin) {
            unsigned total;
            do {
                __builtin_amdgcn_s_sleep(8);
                total = 0;
                #pragma unroll
                for (int i = 0; i < 8; ++i)
                    total += __hip_atomic_load(&c8[i], __ATOMIC_ACQUIRE,
                                               __HIP_MEMORY_SCOPE_AGENT);
            } while (total < GRID);
        }
    }
    __syncthreads();
    __threadfence();
}

// cq index: idx(q',q) = q'(q'+1)/2 + q, valid for q <= q'
#define CQI(QP, Q) ((QP) * ((QP) + 1) / 2 + (Q))

__global__ __launch_bounds__(256, 2)
void fused_kernel(const float* __restrict__ score, const float* __restrict__ box,
                  u64* __restrict__ mask, int* __restrict__ rank_part,
                  int* __restrict__ order, float* __restrict__ s_s,
                  float4* __restrict__ bbox, float* __restrict__ area,
                  unsigned* __restrict__ bars, float* __restrict__ out) {
    __shared__ __align__(16) char smem[4608];   // keys(4KB) | jb(1KB)+ja(256B)
    __shared__ int kpos[MAX_OUT];
    const int bx = blockIdx.x, tid = threadIdx.x;

    // ================= Phase 1: partial ranks =================
    {
        u64* keys = (u64*)smem;
        const int jc = bx >> 5, ic = bx & 31;
        const int jbase = jc * 512;
        for (int t = tid; t < 512; t += 256)
            keys[t] = score_key(score[jbase + t], jbase + t);
        __syncthreads();
        const int i = ic * 256 + tid;
        const u64 ki = score_key(score[i], i);
        int c = 0;
        #pragma unroll 8
        for (int j = 0; j < 512; ++j) c += (keys[j] < ki) ? 1 : 0;
        rank_part[jc * N + i] = c;
    }
    gbar(bars + 0, true);

    // ================= Phase 2: scatter + precompute =================
    if (bx < 32) {
        const int i = bx * 256 + tid;
        int r = 0;
        #pragma unroll
        for (int p = 0; p < 16; ++p) r += rank_part[p * N + i];
        float s = score[i];
        order[r] = i;
        s_s[r] = s;
        float cx = box[i*16 + 0], cy = box[i*16 + 1];
        float w  = box[i*16 + 2], h  = box[i*16 + 3];
        float hw = w * 0.5f, hh = h * 0.5f;
        float x0 = cx - hw, y0 = cy - hh, x1 = cx + hw, y1 = cy + hh;
        bbox[r] = make_float4(x0, y0, x1, y1);
        area[r] = (x1 - x0) * (y1 - y0);   // replicate ref: area from xyxy
    }
    gbar(bars + 8, true);

    // ================= Phase 3: suppression bitmask =================
    // Valid units (w, iy): w >= 4*iy (superblock-aligned diagonal; nms needs
    // within-superblock lower-triangle words). 2112 units balanced over GRID.
    {
        float4* jb = (float4*)smem;
        float*  ja = (float*)(smem + 1024);
        #pragma unroll 1
        for (int k = 0; k < 5; ++k) {
            int t = k * GRID + bx;
            bool active = (t < 2112);
            int iy = 0, w = 0;
            if (active) {
                #pragma unroll 1
                for (int y = 1; y <= 31; ++y)
                    if (t >= y * (130 - 2 * y)) iy = y;   // P(y)=y(130-2y)
                w = 4 * iy + (t - iy * (130 - 2 * iy));
            }
            __syncthreads();
            if (active && tid < 64) {
                jb[tid] = bbox[w * 64 + tid];
                ja[tid] = area[w * 64 + tid];
            }
            __syncthreads();
            if (active) {
                const int i = iy * 256 + tid;
                if (s_s[i] >= 0.3f) {
                    float4 a = bbox[i];
                    float  aa = area[i];
                    u64 bits = 0;
                    #pragma unroll 8
                    for (int jj = 0; jj < 64; ++jj)
                        bits |= ((u64)iou_gt(a, aa, jb[jj], ja[jj])) << jj;
                    mask[(size_t)i * NW + w] = bits;
                }
            }
        }
    }
    gbar(bars + 16, bx == 0);
    if (bx != 0) return;
    if (tid >= 64) return;

    // ================= Phase 4: serial greedy scan (wave 0) =================
    // 256-box superblocks: 10 cross-quarter words/lane prefetched 1 sb ahead;
    // in-sb resolve is pure ballots; kept rows OR'd R2-style (issue 8, drain).
    const int lane = tid;
    u64 cqc[10], cqn[10];
    float scc[4], scn[4];
    {   // preload superblock 0
        #pragma unroll
        for (int qp = 0; qp < 4; ++qp) {
            int ir = qp * 64 + lane;
            scc[qp] = s_s[ir];
            #pragma unroll
            for (int q = 0; q <= qp; ++q)
                cqc[CQI(qp, q)] = mask[(size_t)ir * NW + q];
        }
    }
    u64 remv0 = 0, remv1 = 0;   // lane l owns words 2l, 2l+1
    int kcount = 0;
    bool done = false;

    #pragma unroll 1
    for (int s = 0; s < 32 && !done; ++s) {
        const int base = s << 8, w0 = s << 2;
        // prefetch superblock s+1
        if (s + 1 < 32) {
            #pragma unroll
            for (int qp = 0; qp < 4; ++qp) {
                int ir = base + 256 + qp * 64 + lane;
                scn[qp] = s_s[ir];
                #pragma unroll
                for (int q = 0; q <= qp; ++q)
                    cqn[CQI(qp, q)] = mask[(size_t)ir * NW + (w0 + 4 + q)];
            }
        }
        // remv words for this superblock via shfl broadcast
        u64 rw0 = shfl_u64((w0 & 1) ? remv1 : remv0, w0 >> 1);
        u64 rw1 = shfl_u64(((w0+1) & 1) ? remv1 : remv0, (w0+1) >> 1);
        u64 rw2 = shfl_u64(((w0+2) & 1) ? remv1 : remv0, (w0+2) >> 1);
        u64 rw3 = shfl_u64(((w0+3) & 1) ? remv1 : remv0, (w0+3) >> 1);
        u64 v0 = __ballot(scc[0] >= 0.3f), v1 = __ballot(scc[1] >= 0.3f);
        u64 v2 = __ballot(scc[2] >= 0.3f), v3 = __ballot(scc[3] >= 0.3f);
        u64 km0 = 0, km1 = 0, km2 = 0, km3 = 0;
        u64 sup1 = 0, sup2 = 0, sup3 = 0;
        // ---- quarter 0 ----
        if (v0 == 0) done = true;
        else {
            u64 todo = v0 & ~rw0;
            while (todo) {
                int l = (int)__builtin_ctzll(todo);
                if (lane == 0) kpos[kcount] = base + l;
                km0 |= 1ull << l; ++kcount;
                todo &= ~(1ull << l);
                if (kcount >= MAX_OUT) { done = true; break; }
                todo &= ~__ballot(((cqc[0] >> l) & 1ull) != 0);
                sup1 |= __ballot(((cqc[1] >> l) & 1ull) != 0);
                sup2 |= __ballot(((cqc[3] >> l) & 1ull) != 0);
                sup3 |= __ballot(((cqc[6] >> l) & 1ull) != 0);
            }
        }
        // ---- quarter 1 ----
        if (!done) {
            if (v1 == 0) done = true;
            else {
                u64 todo = v1 & ~rw1 & ~sup1;
                while (todo) {
                    int l = (int)__builtin_ctzll(todo);
                    if (lane == 0) kpos[kcount] = base + 64 + l;
                    km1 |= 1ull << l; ++kcount;
                    todo &= ~(1ull << l);
                    if (kcount >= MAX_OUT) { done = true; break; }
                    todo &= ~__ballot(((cqc[2] >> l) & 1ull) != 0);
                    sup2 |= __ballot(((cqc[4] >> l) & 1ull) != 0);
                    sup3 |= __ballot(((cqc[7] >> l) & 1ull) != 0);
                }
            }
        }
        // ---- quarter 2 ----
        if (!done) {
            if (v2 == 0) done = true;
            else {
                u64 todo = v2 & ~rw2 & ~sup2;
                while (todo) {
                    int l = (int)__builtin_ctzll(todo);
                    if (lane == 0) kpos[kcount] = base + 128 + l;
                    km2 |= 1ull << l; ++kcount;
                    todo &= ~(1ull << l);
                    if (kcount >= MAX_OUT) { done = true; break; }
                    todo &= ~__ballot(((cqc[5] >> l) & 1ull) != 0);
                    sup3 |= __ballot(((cqc[8] >> l) & 1ull) != 0);
                }
            }
        }
        // ---- quarter 3 ----
        if (!done) {
            if (v3 == 0) done = true;
            else {
                u64 todo = v3 & ~rw3 & ~sup3;
                while (todo) {
                    int l = (int)__builtin_ctzll(todo);
                    if (lane == 0) kpos[kcount] = base + 192 + l;
                    km3 |= 1ull << l; ++kcount;
                    todo &= ~(1ull << l);
                    if (kcount >= MAX_OUT) { done = true; break; }
                    todo &= ~__ballot(((cqc[9] >> l) & 1ull) != 0);
                }
            }
        }
        // ---- row ORs (R2-style: issue up to 8, drain) — future sbs only ----
        if (!done) {
            u64 m0 = km0, m1 = km1, m2 = km2, m3 = km3;
            while (m0 | m1 | m2 | m3) {
                int r[8];
                #pragma unroll
                for (int j = 0; j < 8; ++j) {
                    int rr = -1;
                    if (m0)      { int l = (int)__builtin_ctzll(m0); m0 &= m0 - 1; rr = base + l; }
                    else if (m1) { int l = (int)__builtin_ctzll(m1); m1 &= m1 - 1; rr = base + 64 + l; }
                    else if (m2) { int l = (int)__builtin_ctzll(m2); m2 &= m2 - 1; rr = base + 128 + l; }
                    else if (m3) { int l = (int)__builtin_ctzll(m3); m3 &= m3 - 1; rr = base + 192 + l; }
                    r[j] = rr;
                }
                u64 ra[8], rb[8];
                #pragma unroll
                for (int j = 0; j < 8; ++j) {
                    ra[j] = 0; rb[j] = 0;
                    if (r[j] >= 0) {
                        const u64* rp = mask + (size_t)r[j] * NW + 2 * lane;
                        ra[j] = rp[0]; rb[j] = rp[1];
                    }
                }
                #pragma unroll
                for (int j = 0; j < 8; ++j) { remv0 |= ra[j]; remv1 |= rb[j]; }
            }
            // rotate prefetch
            #pragma unroll
            for (int q = 0; q < 10; ++q) cqc[q] = cqn[q];
            #pragma unroll
            for (int q = 0; q < 4; ++q) scc[q] = scn[q];
        }
    }
    __threadfence_block();
    // outputs: [score 256][box 256*16][valid 256], all float32
    float* out_score = out;
    float* out_box   = out + MAX_OUT;
    float* out_valid = out + MAX_OUT + MAX_OUT * 16;
    const float4* box4 = (const float4*)box;
    float4* ob4 = (float4*)out_box;
    for (int t2 = lane; t2 < MAX_OUT; t2 += 64) {
        if (t2 < kcount) {
            int p = kpos[t2];
            out_score[t2] = s_s[p];
            out_valid[t2] = 1.0f;
            int oi = order[p];
            #pragma unroll
            for (int q = 0; q < 4; ++q) ob4[t2 * 4 + q] = box4[oi * 4 + q];
        } else {
            out_score[t2] = 0.0f;
            out_valid[t2] = 0.0f;
            float4 z = make_float4(0.f, 0.f, 0.f, 0.f);
            #pragma unroll
            for (int q = 0; q < 4; ++q) ob4[t2 * 4 + q] = z;
        }
    }
}

extern "C" void kernel_launch(void* const* d_in, const int* in_sizes, int n_in,
                              void* d_out, int out_size, void* d_ws, size_t ws_size,
                              hipStream_t stream) {
    const float* score = (const float*)d_in[0];   // (8192,1) f32
    const float* box   = (const float*)d_in[1];   // (8192,16) f32
    char* ws = (char*)d_ws;
    u64*      mask      = (u64*)ws;
    int*      rank_part = (int*)ws;               // overlap, dead before mask
    int*      order  = (int*)     (ws + MASK_BYTES);
    float*    s_s    = (float*)   (ws + MASK_BYTES + 32768);
    float4*   bbox   = (float4*)  (ws + MASK_BYTES + 65536);
    float*    area   = (float*)   (ws + MASK_BYTES + 65536 + 131072);
    unsigned* bars   = (unsigned*)(ws + MASK_BYTES + 229376);  // 224 KB

    hipMemsetAsync(bars, 0, 128, stream);   // zero 3x8 barrier counters
    fused_kernel<<<GRID, 256, 0, stream>>>(score, box, mask, rank_part,
                                           order, s_s, bbox, area, bars,
                                           (float*)d_out);
}

// Round 6
// 253.109 us; speedup vs baseline: 2.3541x; 2.3541x over previous
//
#include <hip/hip_runtime.h>
#include <stdint.h>

typedef unsigned long long u64;

#define N 8192
#define NW 128            // 64-bit words per mask row
#define MAX_OUT 256
#define MASK_BYTES ((size_t)N * NW * 8)   // 8 MiB

// ws layout:
//   [0, 8MB)    mask u64[N][NW]
//     overlap (dead before mask_kernel writes):
//       ws+0    rank_part int[8][N]  (256 KB)
//   +8MB        order  int[N]     32 KB
//   +32KB       s_s    float[N]   32 KB
//   +64KB       bbox   float4[N] 128 KB
//   +192KB      area   float[N]   32 KB

// Exact ref-op-order IoU decision (bit-exact vs numpy, proven R1-R5).
__device__ __forceinline__ bool iou_gt(float4 a, float aa, float4 b, float ja) {
    float lx = fmaxf(a.x, b.x), ly = fmaxf(a.y, b.y);
    float rx = fminf(a.z, b.z), ry = fminf(a.w, b.w);
    float ww = fmaxf(rx - lx, 0.0f), hh = fmaxf(ry - ly, 0.0f);
    float inter = ww * hh;
    float denom = ((aa + ja) - inter) + 1e-9f;  // exact ref op order
    float iou = inter / denom;                   // IEEE div, matches np
    return iou > 0.3f;
}

__device__ __forceinline__ u64 shfl_u64(u64 v, int src) {
    unsigned lo = __shfl((unsigned)v, src);
    unsigned hi = __shfl((unsigned)(v >> 32), src);
    return ((u64)hi << 32) | lo;
}

// ---------------- Kernel 1: partial ranks (float compares, float4 LDS) ----------------
// rank = #{j : s_j > s_i  ||  (s_j == s_i && j < i)}  — identical order to the
// u64-key compare (scores in [0,1): no -0/NaN; equal floats ⇔ equal bits).
__global__ __launch_bounds__(256)
void rank_kernel(const float* __restrict__ score, int* __restrict__ rank_part) {
    __shared__ float kj[1024];
    const int tid = threadIdx.x;
    const int jbase = blockIdx.y * 1024;
    for (int t = tid; t < 256; t += 256)
        ((float4*)kj)[t] = ((const float4*)(score + jbase))[t];
    __syncthreads();
    const int i = blockIdx.x * 256 + tid;
    const float si = score[i];
    int c = 0;
    #pragma unroll 4
    for (int j4 = 0; j4 < 256; ++j4) {
        float4 v = ((float4*)kj)[j4];           // wave-broadcast b128
        int jg = jbase + 4 * j4;
        c += (v.x > si) || (v.x == si && (jg + 0) < i);
        c += (v.y > si) || (v.y == si && (jg + 1) < i);
        c += (v.z > si) || (v.z == si && (jg + 2) < i);
        c += (v.w > si) || (v.w == si && (jg + 3) < i);
    }
    rank_part[blockIdx.y * N + i] = c;
}

// ---------------- Kernel 2: scatter to sorted order + precompute ----------------
__global__ __launch_bounds__(256)
void scatter_kernel(const float* __restrict__ score, const float* __restrict__ box,
                    const int* __restrict__ rank_part, int* __restrict__ order,
                    float* __restrict__ s_s, float4* __restrict__ bbox,
                    float* __restrict__ area) {
    int i = blockIdx.x * 256 + threadIdx.x;
    int r = 0;
    #pragma unroll
    for (int p = 0; p < 8; ++p) r += rank_part[p * N + i];
    float s = score[i];
    order[r] = i;
    s_s[r] = s;
    float cx = box[i*16 + 0], cy = box[i*16 + 1];
    float w  = box[i*16 + 2], h  = box[i*16 + 3];
    float hw = w * 0.5f, hh = h * 0.5f;
    float x0 = cx - hw, y0 = cy - hh, x1 = cx + hw, y1 = cy + hh;
    bbox[r] = make_float4(x0, y0, x1, y1);
    area[r] = (x1 - x0) * (y1 - y0);   // replicate ref: area from xyxy
}

// ---------------- Kernel 3: suppression bitmask ----------------
// Writes words w >= 4*(i>>8): upper triangle PLUS within-256-superblock
// lower-left quarters (needed by nms cq words). Unwritten words only ever OR
// garbage into remv words of already-consumed superblocks (harmless).
__global__ __launch_bounds__(256)
void mask_kernel(const float4* __restrict__ bbox, const float* __restrict__ area,
                 const float* __restrict__ s_s, u64* __restrict__ mask) {
    const int w = blockIdx.x;
    const int i = blockIdx.y * 256 + threadIdx.x;
    __shared__ float4 jb[64];
    __shared__ float  ja[64];
    if (threadIdx.x < 64) {
        jb[threadIdx.x] = bbox[w * 64 + threadIdx.x];
        ja[threadIdx.x] = area[w * 64 + threadIdx.x];
    }
    __syncthreads();
    if ((w >> 2) < (i >> 8)) return;   // below superblock diagonal: never read
    if (s_s[i] < 0.3f) return;         // invalid rows: never read
    float4 a = bbox[i];
    float  aa = area[i];
    u64 bits = 0;
    #pragma unroll 8
    for (int jj = 0; jj < 64; ++jj)
        bits |= ((u64)iou_gt(a, aa, jb[jj], ja[jj])) << jj;
    mask[(size_t)i * NW + w] = bits;
}

// cq index: idx(q',q) = q'(q'+1)/2 + q, valid for q <= q'
#define CQI(QP, Q) ((QP) * ((QP) + 1) / 2 + (Q))

// ---------------- Kernel 4: serial greedy scan, 256-box superblocks ----------------
// Per step: prefetch next sb's 10 cross-quarter words + 4 scores (issued
// first, consumed next step); 4 remv shfl-broadcasts; pure-ballot resolve of
// 4 quarters (tile column == row by symmetry); kept rows OR'd R2-style
// (issue up to 16, drain). ~23 active steps → ~23 LLC round trips total.
__global__ __launch_bounds__(64)
void nms_kernel(const u64* __restrict__ mask, const float* __restrict__ s_s,
                const int* __restrict__ order, const float* __restrict__ box,
                float* __restrict__ out) {
    const int lane = threadIdx.x;
    __shared__ int kpos[MAX_OUT];
    u64 cqc[10], cqn[10];
    float scc[4], scn[4];
    #pragma unroll
    for (int q = 0; q < 10; ++q) { cqc[q] = 0; cqn[q] = 0; }
    #pragma unroll
    for (int q = 0; q < 4; ++q) { scc[q] = 0.0f; scn[q] = 0.0f; }
    {   // preload superblock 0
        #pragma unroll
        for (int qp = 0; qp < 4; ++qp) {
            int ir = qp * 64 + lane;
            scc[qp] = s_s[ir];
            #pragma unroll
            for (int q = 0; q <= qp; ++q)
                cqc[CQI(qp, q)] = mask[(size_t)ir * NW + q];
        }
    }
    u64 remv0 = 0, remv1 = 0;   // lane l owns words 2l, 2l+1
    int kcount = 0;
    bool done = false;

    #pragma unroll 1
    for (int s = 0; s < 32 && !done; ++s) {
        const int base = s << 8, w0 = s << 2;
        // ---- prefetch superblock s+1 (consumed next iteration) ----
        if (s + 1 < 32) {
            #pragma unroll
            for (int qp = 0; qp < 4; ++qp) {
                int ir = base + 256 + qp * 64 + lane;
                scn[qp] = s_s[ir];
                #pragma unroll
                for (int q = 0; q <= qp; ++q)
                    cqn[CQI(qp, q)] = mask[(size_t)ir * NW + (w0 + 4 + q)];
            }
        }
        // ---- remv words for this superblock via shfl broadcast ----
        u64 rw0 = shfl_u64((w0 & 1) ? remv1 : remv0, w0 >> 1);
        u64 rw1 = shfl_u64(((w0+1) & 1) ? remv1 : remv0, (w0+1) >> 1);
        u64 rw2 = shfl_u64(((w0+2) & 1) ? remv1 : remv0, (w0+2) >> 1);
        u64 rw3 = shfl_u64(((w0+3) & 1) ? remv1 : remv0, (w0+3) >> 1);
        u64 v0 = __ballot(scc[0] >= 0.3f), v1 = __ballot(scc[1] >= 0.3f);
        u64 v2 = __ballot(scc[2] >= 0.3f), v3 = __ballot(scc[3] >= 0.3f);
        u64 km0 = 0, km1 = 0, km2 = 0, km3 = 0;
        u64 sup1 = 0, sup2 = 0, sup3 = 0;
        // ---- quarter 0 ----
        if (v0 == 0) done = true;
        else {
            u64 todo = v0 & ~rw0;
            while (todo) {
                int l = (int)__builtin_ctzll(todo);
                if (lane == 0) kpos[kcount] = base + l;
                km0 |= 1ull << l; ++kcount;
                todo &= ~(1ull << l);
                if (kcount >= MAX_OUT) { done = true; break; }
                todo &= ~__ballot(((cqc[0] >> l) & 1ull) != 0);
                sup1 |= __ballot(((cqc[1] >> l) & 1ull) != 0);
                sup2 |= __ballot(((cqc[3] >> l) & 1ull) != 0);
                sup3 |= __ballot(((cqc[6] >> l) & 1ull) != 0);
            }
        }
        // ---- quarter 1 ----
        if (!done) {
            if (v1 == 0) done = true;
            else {
                u64 todo = v1 & ~rw1 & ~sup1;
                while (todo) {
                    int l = (int)__builtin_ctzll(todo);
                    if (lane == 0) kpos[kcount] = base + 64 + l;
                    km1 |= 1ull << l; ++kcount;
                    todo &= ~(1ull << l);
                    if (kcount >= MAX_OUT) { done = true; break; }
                    todo &= ~__ballot(((cqc[2] >> l) & 1ull) != 0);
                    sup2 |= __ballot(((cqc[4] >> l) & 1ull) != 0);
                    sup3 |= __ballot(((cqc[7] >> l) & 1ull) != 0);
                }
            }
        }
        // ---- quarter 2 ----
        if (!done) {
            if (v2 == 0) done = true;
            else {
                u64 todo = v2 & ~rw2 & ~sup2;
                while (todo) {
                    int l = (int)__builtin_ctzll(todo);
                    if (lane == 0) kpos[kcount] = base + 128 + l;
                    km2 |= 1ull << l; ++kcount;
                    todo &= ~(1ull << l);
                    if (kcount >= MAX_OUT) { done = true; break; }
                    todo &= ~__ballot(((cqc[5] >> l) & 1ull) != 0);
                    sup3 |= __ballot(((cqc[8] >> l) & 1ull) != 0);
                }
            }
        }
        // ---- quarter 3 ----
        if (!done) {
            if (v3 == 0) done = true;
            else {
                u64 todo = v3 & ~rw3 & ~sup3;
                while (todo) {
                    int l = (int)__builtin_ctzll(todo);
                    if (lane == 0) kpos[kcount] = base + 192 + l;
                    km3 |= 1ull << l; ++kcount;
                    todo &= ~(1ull << l);
                    if (kcount >= MAX_OUT) { done = true; break; }
                    todo &= ~__ballot(((cqc[9] >> l) & 1ull) != 0);
                }
            }
        }
        // ---- row ORs (issue up to 16, drain) — affect future sbs only ----
        if (!done) {
            u64 m0 = km0, m1 = km1, m2 = km2, m3 = km3;
            while (m0 | m1 | m2 | m3) {
                int r[16];
                #pragma unroll
                for (int j = 0; j < 16; ++j) {
                    int rr = -1;
                    if (m0)      { int l = (int)__builtin_ctzll(m0); m0 &= m0 - 1; rr = base + l; }
                    else if (m1) { int l = (int)__builtin_ctzll(m1); m1 &= m1 - 1; rr = base + 64 + l; }
                    else if (m2) { int l = (int)__builtin_ctzll(m2); m2 &= m2 - 1; rr = base + 128 + l; }
                    else if (m3) { int l = (int)__builtin_ctzll(m3); m3 &= m3 - 1; rr = base + 192 + l; }
                    r[j] = rr;
                }
                u64 ra[16], rb[16];
                #pragma unroll
                for (int j = 0; j < 16; ++j) {
                    ra[j] = 0; rb[j] = 0;
                    if (r[j] >= 0) {
                        const u64* rp = mask + (size_t)r[j] * NW + 2 * lane;
                        ra[j] = rp[0]; rb[j] = rp[1];
                    }
                }
                #pragma unroll
                for (int j = 0; j < 16; ++j) { remv0 |= ra[j]; remv1 |= rb[j]; }
            }
            // rotate prefetch
            #pragma unroll
            for (int q = 0; q < 10; ++q) cqc[q] = cqn[q];
            #pragma unroll
            for (int q = 0; q < 4; ++q) scc[q] = scn[q];
        }
    }
    __syncthreads();
    // outputs: [score 256][box 256*16][valid 256], all float32
    float* out_score = out;
    float* out_box   = out + MAX_OUT;
    float* out_valid = out + MAX_OUT + MAX_OUT * 16;
    const float4* box4 = (const float4*)box;
    float4* ob4 = (float4*)out_box;
    for (int t2 = lane; t2 < MAX_OUT; t2 += 64) {
        if (t2 < kcount) {
            int p = kpos[t2];
            out_score[t2] = s_s[p];
            out_valid[t2] = 1.0f;
            int oi = order[p];
            #pragma unroll
            for (int q = 0; q < 4; ++q) ob4[t2 * 4 + q] = box4[oi * 4 + q];
        } else {
            out_score[t2] = 0.0f;
            out_valid[t2] = 0.0f;
            float4 z = make_float4(0.f, 0.f, 0.f, 0.f);
            #pragma unroll
            for (int q = 0; q < 4; ++q) ob4[t2 * 4 + q] = z;
        }
    }
}

extern "C" void kernel_launch(void* const* d_in, const int* in_sizes, int n_in,
                              void* d_out, int out_size, void* d_ws, size_t ws_size,
                              hipStream_t stream) {
    const float* score = (const float*)d_in[0];   // (8192,1) f32
    const float* box   = (const float*)d_in[1];   // (8192,16) f32
    char* ws = (char*)d_ws;
    u64*    mask      = (u64*)ws;
    int*    rank_part = (int*)ws;                 // overlap, dead before mask
    int*    order  = (int*)   (ws + MASK_BYTES);
    float*  s_s    = (float*) (ws + MASK_BYTES + 32768);
    float4* bbox   = (float4*)(ws + MASK_BYTES + 65536);
    float*  area   = (float*) (ws + MASK_BYTES + 65536 + 131072);

    rank_kernel<<<dim3(32, 8), 256, 0, stream>>>(score, rank_part);
    scatter_kernel<<<32, 256, 0, stream>>>(score, box, rank_part, order, s_s, bbox, area);
    mask_kernel<<<dim3(128, 32), 256, 0, stream>>>(bbox, area, s_s, mask);
    nms_kernel<<<1, 64, 0, stream>>>(mask, s_s, order, box, (float*)d_out);
}

// Round 7
// 207.884 us; speedup vs baseline: 2.8662x; 1.2175x over previous
//
#include <hip/hip_runtime.h>
#include <stdint.h>

typedef unsigned long long u64;

#define N 8192
#define NW 128            // 64-bit words per mask row
#define MAX_OUT 256
#define MASK_BYTES ((size_t)N * NW * 8)   // 8 MiB

// ws layout:
//   [0, 8MB)    mask u64[N][NW]
//     overlap (dead before mask_kernel writes):
//       ws+0    rank_part int[8][N]  (256 KB)
//   +8MB        order  int[N]     32 KB
//   +32KB       s_s    float[N]   32 KB
//   +64KB       bbox   float4[N] 128 KB
//   +192KB      area   float[N]   32 KB

// Exact ref-op-order IoU decision (bit-exact vs numpy, proven R1-R6).
__device__ __forceinline__ bool iou_gt(float4 a, float aa, float4 b, float ja) {
    float lx = fmaxf(a.x, b.x), ly = fmaxf(a.y, b.y);
    float rx = fminf(a.z, b.z), ry = fminf(a.w, b.w);
    float ww = fmaxf(rx - lx, 0.0f), hh = fmaxf(ry - ly, 0.0f);
    float inter = ww * hh;
    float denom = ((aa + ja) - inter) + 1e-9f;  // exact ref op order
    float iou = inter / denom;                   // IEEE div, matches np
    return iou > 0.3f;
}

__device__ __forceinline__ u64 shfl_u64(u64 v, int src) {
    unsigned lo = __shfl((unsigned)v, src);
    unsigned hi = __shfl((unsigned)(v >> 32), src);
    return ((u64)hi << 32) | lo;
}

// Async global->LDS copy, 16 B/lane. gptr is PER-LANE; data lands at
// ldsbase + lane*16 (wave-uniform base — m104/m108 semantics). No dest VGPR
// => no data-dependency waitcnt; drained explicitly by __syncthreads().
__device__ __forceinline__ void gload_lds16(const void* g, void* l) {
    __builtin_amdgcn_global_load_lds(
        (const __attribute__((address_space(1))) unsigned int*)g,
        (__attribute__((address_space(3))) unsigned int*)l, 16, 0, 0);
}

// ---------------- Kernel 1: partial ranks (float compares, float4 LDS) ----------------
__global__ __launch_bounds__(256)
void rank_kernel(const float* __restrict__ score, int* __restrict__ rank_part) {
    __shared__ float kj[1024];
    const int tid = threadIdx.x;
    const int jbase = blockIdx.y * 1024;
    for (int t = tid; t < 256; t += 256)
        ((float4*)kj)[t] = ((const float4*)(score + jbase))[t];
    __syncthreads();
    const int i = blockIdx.x * 256 + tid;
    const float si = score[i];
    int c = 0;
    #pragma unroll 4
    for (int j4 = 0; j4 < 256; ++j4) {
        float4 v = ((float4*)kj)[j4];           // wave-broadcast b128
        int jg = jbase + 4 * j4;
        c += (v.x > si) || (v.x == si && (jg + 0) < i);
        c += (v.y > si) || (v.y == si && (jg + 1) < i);
        c += (v.z > si) || (v.z == si && (jg + 2) < i);
        c += (v.w > si) || (v.w == si && (jg + 3) < i);
    }
    rank_part[blockIdx.y * N + i] = c;
}

// ---------------- Kernel 2: scatter to sorted order + precompute ----------------
__global__ __launch_bounds__(256)
void scatter_kernel(const float* __restrict__ score, const float* __restrict__ box,
                    const int* __restrict__ rank_part, int* __restrict__ order,
                    float* __restrict__ s_s, float4* __restrict__ bbox,
                    float* __restrict__ area) {
    int i = blockIdx.x * 256 + threadIdx.x;
    int r = 0;
    #pragma unroll
    for (int p = 0; p < 8; ++p) r += rank_part[p * N + i];
    float s = score[i];
    order[r] = i;
    s_s[r] = s;
    float cx = box[i*16 + 0], cy = box[i*16 + 1];
    float w  = box[i*16 + 2], h  = box[i*16 + 3];
    float hw = w * 0.5f, hh = h * 0.5f;
    float x0 = cx - hw, y0 = cy - hh, x1 = cx + hw, y1 = cy + hh;
    bbox[r] = make_float4(x0, y0, x1, y1);
    area[r] = (x1 - x0) * (y1 - y0);   // replicate ref: area from xyxy
}

// ---------------- Kernel 3: suppression bitmask ----------------
// Writes words w >= 4*(i>>8): upper triangle PLUS within-256-superblock
// lower-left quarters (needed by nms cq words). Unwritten words are never read.
__global__ __launch_bounds__(256)
void mask_kernel(const float4* __restrict__ bbox, const float* __restrict__ area,
                 const float* __restrict__ s_s, u64* __restrict__ mask) {
    const int w = blockIdx.x;
    const int i = blockIdx.y * 256 + threadIdx.x;
    __shared__ float4 jb[64];
    __shared__ float  ja[64];
    if (threadIdx.x < 64) {
        jb[threadIdx.x] = bbox[w * 64 + threadIdx.x];
        ja[threadIdx.x] = area[w * 64 + threadIdx.x];
    }
    __syncthreads();
    if ((w >> 2) < (i >> 8)) return;   // below superblock diagonal: never read
    if (s_s[i] < 0.3f) return;         // invalid rows: never read
    float4 a = bbox[i];
    float  aa = area[i];
    u64 bits = 0;
    #pragma unroll 8
    for (int jj = 0; jj < 64; ++jj)
        bits |= ((u64)iou_gt(a, aa, jb[jj], ja[jj])) << jj;
    mask[(size_t)i * NW + w] = bits;
}

// cq index: idx(q',q) = q'(q'+1)/2 + q, valid for q <= q'
#define CQI(QP, Q) ((QP) * ((QP) + 1) / 2 + (Q))

// ---------------- Kernel 4: serial greedy scan, async-LDS memory machinery ----------------
// Per 256-box superblock: cq words come from an LDS double-buffer filled by 8
// async 16B-gather global_load_lds issued LAST iteration; kept rows are copied
// 1 KB each by ONE async instruction (64 lanes x 16 B); a single __syncthreads
// per sb drains everything => ~1 LLC round trip per superblock (vs ~12 in R6).
// All async issues are in wave-uniform control flow.
__global__ __launch_bounds__(64)
void nms_kernel(const u64* __restrict__ mask, const float* __restrict__ s_s,
                const int* __restrict__ order, const float* __restrict__ box,
                float* __restrict__ out) {
    const int lane = threadIdx.x;
    __shared__ u64 rowbuf[16][128];    // 16 KB: 16 row-copy slots (1 KB rows)
    __shared__ u64 cqbuf[2][8][128];   // 16 KB: dbuf x (qp*2+chunk) x (lane*2+w)
    __shared__ int kpos[MAX_OUT];
    u64 remv0 = 0, remv1 = 0;          // lane l owns words 2l, 2l+1
    int kcount = 0;
    bool done = false;
    float scc[4], scn[4];

    // preload superblock 0: scores (regs) + cq words 0..3 (async into cqbuf[0])
    #pragma unroll
    for (int qp = 0; qp < 4; ++qp) {
        int ir = qp * 64 + lane;
        scc[qp] = s_s[ir];
        #pragma unroll
        for (int c = 0; c < 2; ++c)
            gload_lds16(&mask[(size_t)ir * NW + 2 * c], &cqbuf[0][qp * 2 + c][0]);
    }
    __syncthreads();

    #pragma unroll 1
    for (int s = 0; s < 32 && !done; ++s) {
        const int base = s << 8, w0 = s << 2, ss = s & 1;
        // ---- read this sb's cq words from LDS ----
        u64 cq[10];
        #pragma unroll
        for (int qp = 0; qp < 4; ++qp)
            #pragma unroll
            for (int q = 0; q <= qp; ++q)
                cq[CQI(qp, q)] = cqbuf[ss][qp * 2 + (q >> 1)][2 * lane + (q & 1)];
        // ---- remv words via shfl broadcast ----
        u64 rw0 = shfl_u64((w0 & 1) ? remv1 : remv0, w0 >> 1);
        u64 rw1 = shfl_u64(((w0+1) & 1) ? remv1 : remv0, (w0+1) >> 1);
        u64 rw2 = shfl_u64(((w0+2) & 1) ? remv1 : remv0, (w0+2) >> 1);
        u64 rw3 = shfl_u64(((w0+3) & 1) ? remv1 : remv0, (w0+3) >> 1);
        u64 v0 = __ballot(scc[0] >= 0.3f), v1 = __ballot(scc[1] >= 0.3f);
        u64 v2 = __ballot(scc[2] >= 0.3f), v3 = __ballot(scc[3] >= 0.3f);
        u64 km0 = 0, km1 = 0, km2 = 0, km3 = 0;
        u64 sup1 = 0, sup2 = 0, sup3 = 0;
        // ---- quarter 0 ----
        if (v0 == 0) done = true;
        else {
            u64 todo = v0 & ~rw0;
            while (todo) {
                int l = (int)__builtin_ctzll(todo);
                if (lane == 0) kpos[kcount] = base + l;
                km0 |= 1ull << l; ++kcount;
                todo &= ~(1ull << l);
                if (kcount >= MAX_OUT) { done = true; break; }
                todo &= ~__ballot(((cq[0] >> l) & 1ull) != 0);
                sup1 |= __ballot(((cq[1] >> l) & 1ull) != 0);
                sup2 |= __ballot(((cq[3] >> l) & 1ull) != 0);
                sup3 |= __ballot(((cq[6] >> l) & 1ull) != 0);
            }
        }
        // ---- quarter 1 ----
        if (!done) {
            if (v1 == 0) done = true;
            else {
                u64 todo = v1 & ~rw1 & ~sup1;
                while (todo) {
                    int l = (int)__builtin_ctzll(todo);
                    if (lane == 0) kpos[kcount] = base + 64 + l;
                    km1 |= 1ull << l; ++kcount;
                    todo &= ~(1ull << l);
                    if (kcount >= MAX_OUT) { done = true; break; }
                    todo &= ~__ballot(((cq[2] >> l) & 1ull) != 0);
                    sup2 |= __ballot(((cq[4] >> l) & 1ull) != 0);
                    sup3 |= __ballot(((cq[7] >> l) & 1ull) != 0);
                }
            }
        }
        // ---- quarter 2 ----
        if (!done) {
            if (v2 == 0) done = true;
            else {
                u64 todo = v2 & ~rw2 & ~sup2;
                while (todo) {
                    int l = (int)__builtin_ctzll(todo);
                    if (lane == 0) kpos[kcount] = base + 128 + l;
                    km2 |= 1ull << l; ++kcount;
                    todo &= ~(1ull << l);
                    if (kcount >= MAX_OUT) { done = true; break; }
                    todo &= ~__ballot(((cq[5] >> l) & 1ull) != 0);
                    sup3 |= __ballot(((cq[8] >> l) & 1ull) != 0);
                }
            }
        }
        // ---- quarter 3 ----
        if (!done) {
            if (v3 == 0) done = true;
            else {
                u64 todo = v3 & ~rw3 & ~sup3;
                while (todo) {
                    int l = (int)__builtin_ctzll(todo);
                    if (lane == 0) kpos[kcount] = base + 192 + l;
                    km3 |= 1ull << l; ++kcount;
                    todo &= ~(1ull << l);
                    if (kcount >= MAX_OUT) { done = true; break; }
                    todo &= ~__ballot(((cq[9] >> l) & 1ull) != 0);
                }
            }
        }
        if (done) break;
        // ---- issue prefetch for sb s+1 (other cq buffer) ----
        if (s + 1 < 32) {
            #pragma unroll
            for (int qp = 0; qp < 4; ++qp) {
                int ir = base + 256 + qp * 64 + lane;
                scn[qp] = s_s[ir];
                #pragma unroll
                for (int c = 0; c < 2; ++c)
                    gload_lds16(&mask[(size_t)ir * NW + (w0 + 4 + 2 * c)],
                                &cqbuf[ss ^ 1][qp * 2 + c][0]);
            }
        } else {
            #pragma unroll
            for (int qp = 0; qp < 4; ++qp) scn[qp] = 0.0f;
        }
        // ---- kept-row ORs: 1 async instr per row (full 1 KB), groups of 16 ----
        u64 m0 = km0, m1 = km1, m2 = km2, m3 = km3;
        int ngroups = 0;
        while (m0 | m1 | m2 | m3) {
            int rows[16];
            #pragma unroll
            for (int j = 0; j < 16; ++j) {
                int rr = -1;
                if (m0)      { int l = (int)__builtin_ctzll(m0); m0 &= m0 - 1; rr = base + l; }
                else if (m1) { int l = (int)__builtin_ctzll(m1); m1 &= m1 - 1; rr = base + 64 + l; }
                else if (m2) { int l = (int)__builtin_ctzll(m2); m2 &= m2 - 1; rr = base + 128 + l; }
                else if (m3) { int l = (int)__builtin_ctzll(m3); m3 &= m3 - 1; rr = base + 192 + l; }
                rows[j] = rr;
            }
            #pragma unroll
            for (int j = 0; j < 16; ++j)
                if (rows[j] >= 0)
                    gload_lds16(&mask[(size_t)rows[j] * NW + 2 * lane], &rowbuf[j][0]);
            __syncthreads();   // drains row copies AND the cq prefetch
            #pragma unroll
            for (int j = 0; j < 16; ++j)
                if (rows[j] >= 0) {
                    remv0 |= rowbuf[j][2 * lane];
                    remv1 |= rowbuf[j][2 * lane + 1];
                }
            ++ngroups;
        }
        if (ngroups == 0) __syncthreads();   // still must drain the prefetch
        // ---- rotate scores ----
        #pragma unroll
        for (int qp = 0; qp < 4; ++qp) scc[qp] = scn[qp];
    }
    __syncthreads();
    // outputs: [score 256][box 256*16][valid 256], all float32
    float* out_score = out;
    float* out_box   = out + MAX_OUT;
    float* out_valid = out + MAX_OUT + MAX_OUT * 16;
    const float4* box4 = (const float4*)box;
    float4* ob4 = (float4*)out_box;
    for (int t2 = lane; t2 < MAX_OUT; t2 += 64) {
        if (t2 < kcount) {
            int p = kpos[t2];
            out_score[t2] = s_s[p];
            out_valid[t2] = 1.0f;
            int oi = order[p];
            #pragma unroll
            for (int q = 0; q < 4; ++q) ob4[t2 * 4 + q] = box4[oi * 4 + q];
        } else {
            out_score[t2] = 0.0f;
            out_valid[t2] = 0.0f;
            float4 z = make_float4(0.f, 0.f, 0.f, 0.f);
            #pragma unroll
            for (int q = 0; q < 4; ++q) ob4[t2 * 4 + q] = z;
        }
    }
}

extern "C" void kernel_launch(void* const* d_in, const int* in_sizes, int n_in,
                              void* d_out, int out_size, void* d_ws, size_t ws_size,
                              hipStream_t stream) {
    const float* score = (const float*)d_in[0];   // (8192,1) f32
    const float* box   = (const float*)d_in[1];   // (8192,16) f32
    char* ws = (char*)d_ws;
    u64*    mask      = (u64*)ws;
    int*    rank_part = (int*)ws;                 // overlap, dead before mask
    int*    order  = (int*)   (ws + MASK_BYTES);
    float*  s_s    = (float*) (ws + MASK_BYTES + 32768);
    float4* bbox   = (float4*)(ws + MASK_BYTES + 65536);
    float*  area   = (float*) (ws + MASK_BYTES + 65536 + 131072);

    rank_kernel<<<dim3(32, 8), 256, 0, stream>>>(score, rank_part);
    scatter_kernel<<<32, 256, 0, stream>>>(score, box, rank_part, order, s_s, bbox, area);
    mask_kernel<<<dim3(128, 32), 256, 0, stream>>>(bbox, area, s_s, mask);
    nms_kernel<<<1, 64, 0, stream>>>(mask, s_s, order, box, (float*)d_out);
}